// Round 1
// baseline (169.380 us; speedup 1.0000x reference)
//
#include <hip/hip_runtime.h>
#include <hip/hip_bf16.h>
#include <stdint.h>

#define B_ 64
#define T_ 20
#define N_ 8192
#define E_ 128
#define H_ 128
#define G4 512

typedef short bf16x8 __attribute__((ext_vector_type(8)));
typedef float f32x4 __attribute__((ext_vector_type(4)));

__device__ __forceinline__ float sigmoidf_(float x){ return 1.0f/(1.0f+expf(-x)); }

__device__ __forceinline__ unsigned short f2bf(float f){
  union { float f; uint32_t u; } v; v.f = f;
  uint32_t u = v.u;
  uint32_t r = (u + 0x7FFFu + ((u >> 16) & 1u)) >> 16;
  return (unsigned short)r;
}
__device__ __forceinline__ uint32_t pk2(float a, float b){
  return (uint32_t)f2bf(a) | ((uint32_t)f2bf(b) << 16);
}

// ---------------- 1. transpose W1,W2 -> W12T[n][0:128]=W1[:,n], [128:256]=W2[:,n]
__global__ void k_transpose(const float* __restrict__ W1, const float* __restrict__ W2,
                            float* __restrict__ W12T){
  __shared__ float t1[128][33];
  __shared__ float t2[128][33];
  int n0 = blockIdx.x * 32;
  int tid = threadIdx.x;           // 256
  int nl = tid & 31, eg = tid >> 5;
  for (int i = 0; i < 16; i++){
    int e = eg * 16 + i;
    t1[e][nl] = W1[(size_t)e*N_ + n0 + nl];
    t2[e][nl] = W2[(size_t)e*N_ + n0 + nl];
  }
  __syncthreads();
  for (int n = 0; n < 32; n++){
    float v = (tid < 128) ? t1[tid][n] : t2[tid-128][n];
    W12T[(size_t)(n0+n)*256 + tid] = v;
  }
}

// ---------------- 2. sparse MLP: basket[bt][e] = max(relu(sum W1col + b1), relu(sum W2col + b2))
__global__ void k_mlp(const float* __restrict__ x, const int* __restrict__ seq_len,
                      const float* __restrict__ W12T, const float* __restrict__ b1,
                      const float* __restrict__ b2, float* __restrict__ basket){
  int bt = blockIdx.x;
  int b = bt / T_, t = bt % T_;
  if (t >= seq_len[b]) return;     // invalid steps never consumed
  __shared__ int idxs[1024];
  __shared__ int cnt;
  __shared__ float e2s[128];
  int tid = threadIdx.x;           // 256
  if (tid == 0) cnt = 0;
  __syncthreads();
  const float4* xr = (const float4*)(x + (size_t)bt * N_);
  for (int i = 0; i < 8; i++){
    float4 v = xr[i*256 + tid];
    int base = (i*256 + tid)*4;
    if (v.x != 0.f){ int q = atomicAdd(&cnt,1); idxs[q] = base;   }
    if (v.y != 0.f){ int q = atomicAdd(&cnt,1); idxs[q] = base+1; }
    if (v.z != 0.f){ int q = atomicAdd(&cnt,1); idxs[q] = base+2; }
    if (v.w != 0.f){ int q = atomicAdd(&cnt,1); idxs[q] = base+3; }
  }
  __syncthreads();
  int m = cnt; if (m > 1024) m = 1024;
  float acc = (tid < 128) ? b1[tid] : b2[tid-128];
  for (int i = 0; i < m; i++)
    acc += W12T[(size_t)idxs[i]*256 + tid];
  acc = fmaxf(acc, 0.f);
  if (tid >= 128) e2s[tid-128] = acc;
  __syncthreads();
  if (tid < 128) basket[(size_t)bt*E_ + tid] = fmaxf(acc, e2s[tid]);
}

// ---------------- 3. Xp[bt][j] = b_ih[j]+b_hh[j] + basket[bt] . W_ih[j,:]
__global__ void k_xproj(const int* __restrict__ seq_len, const float* __restrict__ basket,
                        const float* __restrict__ W_ih, const float* __restrict__ b_ih,
                        const float* __restrict__ b_hh, float* __restrict__ Xp){
  int bt = blockIdx.x;
  int b = bt / T_, t = bt % T_;
  if (t >= seq_len[b]) return;
  __shared__ float xv[128];
  int tid = threadIdx.x;           // 512
  if (tid < 128) xv[tid] = basket[(size_t)bt*E_ + tid];
  __syncthreads();
  const float4* wr = (const float4*)(W_ih + (size_t)tid * E_);
  float acc = b_ih[tid] + b_hh[tid];
  #pragma unroll
  for (int k4 = 0; k4 < 32; k4++){
    float4 w = wr[k4];
    float4 h = *(const float4*)&xv[k4*4];
    acc += w.x*h.x + w.y*h.y + w.z*h.z + w.w*h.w;
  }
  Xp[(size_t)bt*G4 + tid] = acc;
}

// ---------------- 4. LSTM: one block per batch row, W_hh row register-cached
__global__ void __launch_bounds__(512, 2)
k_lstm(const int* __restrict__ seq_len, const float* __restrict__ Xp,
       const float* __restrict__ W_hh, float* __restrict__ hn){
  int b = blockIdx.x;
  int L = seq_len[b];
  int j = threadIdx.x;             // 512
  float4 whh[32];
  const float4* wr = (const float4*)(W_hh + (size_t)j * H_);
  #pragma unroll
  for (int k = 0; k < 32; k++) whh[k] = wr[k];
  __shared__ float hs[128];
  __shared__ float gs[512];
  if (j < 128) hs[j] = 0.f;
  float c = 0.f;
  __syncthreads();
  for (int t = 0; t < L; t++){
    float g = Xp[((size_t)b*T_ + t)*G4 + j];
    #pragma unroll
    for (int k = 0; k < 32; k++){
      float4 h = *(const float4*)&hs[k*4];
      float4 w = whh[k];
      g += w.x*h.x + w.y*h.y + w.z*h.z + w.w*h.w;
    }
    gs[j] = g;
    __syncthreads();
    if (j < 128){
      float i_ = gs[j], f_ = gs[128+j], gg = gs[256+j], o_ = gs[384+j];
      c = sigmoidf_(f_)*c + sigmoidf_(i_)*tanhf(gg);
      hs[j] = sigmoidf_(o_)*tanhf(c);
    }
    __syncthreads();
  }
  if (j < 128) hn[(size_t)b*H_ + j] = hs[j];
}

// ---------------- 5. p = sigmoid(hn @ W_out^T) via MFMA; also emit bf16 copy
__global__ void k_pout(const float* __restrict__ hn, const float* __restrict__ W_out,
                       float* __restrict__ p, unsigned short* __restrict__ pbf){
  __shared__ unsigned short hb[64*128];   // bf16, XOR-swizzled 16B blocks
  int tid = threadIdx.x;                  // 256
  {
    int row = tid >> 2;
    int k16 = (tid & 3) * 32;
    const float4* hr = (const float4*)(hn + (size_t)row*H_ + k16);
    #pragma unroll
    for (int i = 0; i < 4; i++){
      float4 a = hr[i*2], bq = hr[i*2+1];
      uint4 u; u.x = pk2(a.x,a.y); u.y = pk2(a.z,a.w); u.z = pk2(bq.x,bq.y); u.w = pk2(bq.z,bq.w);
      int blk = (k16 >> 3) + i;
      *(uint4*)&hb[row*128 + ((blk ^ (row & 7)) * 8)] = u;
    }
  }
  __syncthreads();
  int w = tid >> 6, l = tid & 63;
  int n0 = blockIdx.x * 128;
  f32x4 acc[8];
  #pragma unroll
  for (int i = 0; i < 8; i++) acc[i] = (f32x4){0.f,0.f,0.f,0.f};
  int row = w*16 + (l & 15);
  #pragma unroll
  for (int ks = 0; ks < 4; ks++){
    int kk = ks*32 + (l >> 4)*8;
    int blk = kk >> 3;
    bf16x8 af = *(bf16x8*)&hb[row*128 + ((blk ^ (row & 7)) * 8)];
    #pragma unroll
    for (int nt = 0; nt < 8; nt++){
      int n = n0 + nt*16 + (l & 15);
      const float4* wp = (const float4*)(W_out + (size_t)n*H_ + kk);
      float4 wa = wp[0], wb = wp[1];
      union { uint4 u; bf16x8 v; } cc;
      cc.u.x = pk2(wa.x,wa.y); cc.u.y = pk2(wa.z,wa.w);
      cc.u.z = pk2(wb.x,wb.y); cc.u.w = pk2(wb.z,wb.w);
      acc[nt] = __builtin_amdgcn_mfma_f32_16x16x32_bf16(af, cc.v, acc[nt], 0, 0, 0);
    }
  }
  #pragma unroll
  for (int nt = 0; nt < 8; nt++){
    int n = n0 + nt*16 + (l & 15);
    #pragma unroll
    for (int r = 0; r < 4; r++){
      int rr = w*16 + (l >> 4)*4 + r;
      float pv = 1.f/(1.f + expf(-acc[nt][r]));
      p[(size_t)rr*N_ + n] = pv;
      pbf[(size_t)rr*N_ + n] = f2bf(pv);
    }
  }
}

// ---------------- 6. C += p @ A  (split-K, fused fp32->bf16, MFMA)
__global__ void __launch_bounds__(256, 2)
k_gemm(const unsigned short* __restrict__ pbf, const float* __restrict__ Ag,
       float* __restrict__ C){
  __shared__ unsigned short Abf[128*32];  // [n][k] bf16, k4^((n&3)*8) swizzle
  __shared__ unsigned short pt[64*32];    // [b][k] bf16 linear
  int tid = threadIdx.x;                  // 256
  int nb = blockIdx.x & 63, ks = blockIdx.x >> 6;
  int n0 = nb * 128;
  int kbase = ks * 1024;
  int w = tid >> 6, l = tid & 63;
  f32x4 acc[8];
  #pragma unroll
  for (int i = 0; i < 8; i++) acc[i] = (f32x4){0.f,0.f,0.f,0.f};
  int sn = tid & 127, kq = tid >> 7;
  int prow = tid >> 2, phw = (tid & 3) * 8;

  for (int step = 0; step < 32; step++){
    int kb = kbase + step*32;
    // stage p tile (bf16, linear)
    *(uint4*)&pt[prow*32 + phw] = *(const uint4*)&pbf[(size_t)prow*N_ + kb + phw];
    // stage A tile: transpose+convert via regs, swizzled ds_write_b64
    #pragma unroll
    for (int i = 0; i < 4; i++){
      int k4 = kq*16 + i*4;
      float v0 = Ag[(size_t)(kb + k4 + 0)*N_ + n0 + sn];
      float v1 = Ag[(size_t)(kb + k4 + 1)*N_ + n0 + sn];
      float v2 = Ag[(size_t)(kb + k4 + 2)*N_ + n0 + sn];
      float v3 = Ag[(size_t)(kb + k4 + 3)*N_ + n0 + sn];
      uint2 u; u.x = pk2(v0,v1); u.y = pk2(v2,v3);
      *(uint2*)&Abf[sn*32 + (k4 ^ ((sn & 3) * 8))] = u;
    }
    __syncthreads();
    bf16x8 af = *(bf16x8*)&pt[(w*16 + (l & 15))*32 + (l >> 4)*8];
    #pragma unroll
    for (int nt = 0; nt < 8; nt++){
      int n = nt*16 + (l & 15);
      bf16x8 bfr = *(bf16x8*)&Abf[n*32 + (((l >> 4)*8) ^ ((n & 3)*8))];
      acc[nt] = __builtin_amdgcn_mfma_f32_16x16x32_bf16(af, bfr, acc[nt], 0, 0, 0);
    }
    __syncthreads();
  }
  #pragma unroll
  for (int nt = 0; nt < 8; nt++){
    int n = n0 + nt*16 + (l & 15);
    #pragma unroll
    for (int r = 0; r < 4; r++){
      int rr = w*16 + (l >> 4)*4 + r;
      atomicAdd(&C[(size_t)rr*N_ + n], acc[nt][r]);
    }
  }
}

// ---------------- 7. final blend
__global__ void k_final(const float* __restrict__ p, const float* __restrict__ C,
                        const float* __restrict__ I_B, float* __restrict__ out){
  int idx = blockIdx.x*256 + threadIdx.x;
  float4 pv = ((const float4*)p)[idx];
  float4 cv = ((const float4*)C)[idx];
  int n = (idx*4) & (N_-1);
  float4 ib = *(const float4*)&I_B[n];
  float4 o;
  o.x = 0.5f*pv.x + 0.5f*(pv.x*fmaxf(ib.x,0.f) + fmaxf(cv.x,0.f));
  o.y = 0.5f*pv.y + 0.5f*(pv.y*fmaxf(ib.y,0.f) + fmaxf(cv.y,0.f));
  o.z = 0.5f*pv.z + 0.5f*(pv.z*fmaxf(ib.z,0.f) + fmaxf(cv.z,0.f));
  o.w = 0.5f*pv.w + 0.5f*(pv.w*fmaxf(ib.w,0.f) + fmaxf(cv.w,0.f));
  ((float4*)out)[idx] = o;
}

extern "C" void kernel_launch(void* const* d_in, const int* in_sizes, int n_in,
                              void* d_out, int out_size, void* d_ws, size_t ws_size,
                              hipStream_t stream) {
  const float* x     = (const float*)d_in[0];
  const int*   seq   = (const int*)  d_in[1];
  const float* A     = (const float*)d_in[2];
  const float* W1    = (const float*)d_in[3];
  const float* b1    = (const float*)d_in[4];
  const float* W2    = (const float*)d_in[5];
  const float* b2    = (const float*)d_in[6];
  const float* W_ih  = (const float*)d_in[7];
  const float* W_hh  = (const float*)d_in[8];
  const float* b_ih  = (const float*)d_in[9];
  const float* b_hh  = (const float*)d_in[10];
  const float* W_out = (const float*)d_in[11];
  const float* I_B   = (const float*)d_in[12];
  float* out = (float*)d_out;

  float* ws     = (float*)d_ws;
  float* W12T   = ws;                       // 8192*256   = 2,097,152
  float* basket = W12T + 2097152;           // 1280*128   =   163,840
  float* Xp     = basket + 163840;          // 1280*512   =   655,360
  float* hn     = Xp + 655360;              // 64*128     =     8,192
  float* p      = hn + 8192;                // 64*8192    =   524,288
  float* C      = p + 524288;               // 64*8192    =   524,288
  unsigned short* pbf = (unsigned short*)(C + 524288); // 64*8192 bf16

  hipMemsetAsync(C, 0, 524288*sizeof(float), stream);
  k_transpose<<<256, 256, 0, stream>>>(W1, W2, W12T);
  k_mlp      <<<1280,256, 0, stream>>>(x, seq, W12T, b1, b2, basket);
  k_xproj    <<<1280,512, 0, stream>>>(seq, basket, W_ih, b_ih, b_hh, Xp);
  k_lstm     <<<64,  512, 0, stream>>>(seq, Xp, W_hh, hn);
  k_pout     <<<64,  256, 0, stream>>>(hn, W_out, p, pbf);
  k_gemm     <<<512, 256, 0, stream>>>(pbf, A, C);
  k_final    <<<512, 256, 0, stream>>>(p, C, I_B, out);
}